// Round 1
// baseline (263.803 us; speedup 1.0000x reference)
//
#include <hip/hip_runtime.h>

#define Bc  4
#define NFc 5
#define HSc 512
#define Sc  1024
#define WSr (Sc - 2)            // 1022, w_inner row length
#define WSp ((HSc - 2) * WSr)   // w_inner plane stride
#define PS  (HSc * Sc)          // x/out plane stride (per f)

typedef float f4 __attribute__((ext_vector_type(4)));

// unaligned (4B-aligned) 16-byte load
static __device__ __forceinline__ f4 load4u(const float* p) {
    f4 r;
    __builtin_memcpy(&r, p, 16);
    return r;
}

#define X(ff,jj,ii) x[xb + ((size_t)(ff) * HSc + (size_t)(jj)) * Sc + (size_t)(ii)]

__global__ __launch_bounds__(256) void icograd_fused(
    const float* __restrict__ x,    const float* __restrict__ poles,
    const float* __restrict__ wi,   const float* __restrict__ we,
    const float* __restrict__ wcn,  const float* __restrict__ wne,
    const float* __restrict__ wnne, const float* __restrict__ wnw,
    const float* __restrict__ wnww, const float* __restrict__ wwe,
    const float* __restrict__ wsw,  const float* __restrict__ wsse,
    const float* __restrict__ wse,  const float* __restrict__ wcs,
    float* __restrict__ out)
{
    const int t = threadIdx.x;
    const int b = blockIdx.y;

    const size_t xb  = (size_t)b * (NFc * PS);
    const size_t cs  = (size_t)NFc * PS;                // component stride in out
    const size_t obB = (size_t)b * (4 * NFc) * PS;      // out base for this b

    if (blockIdx.x >= 8) {
        // =============== bulk rows 1..510, one row per block, loop f ===============
        const int j  = blockIdx.x - 7;      // 1..510
        const int m  = j - 1;
        const int i0 = t * 4;

        if (t >= 1 && t <= 254) {
            // ---- vector path: cols i0..i0+3, all inner; w loaded ONCE ----
            const float* wrow = wi + (size_t)m * WSr + (i0 - 1);
            const f4 w0 = load4u(wrow);
            const f4 w1 = load4u(wrow + (size_t)WSp);
            const f4 w2 = load4u(wrow + 2 * (size_t)WSp);
            const f4 w3 = load4u(wrow + 3 * (size_t)WSp);
            const f4 w4 = load4u(wrow + 4 * (size_t)WSp);
            const f4 w5 = load4u(wrow + 5 * (size_t)WSp);
            const float w0v[4] = {w0.x, w0.y, w0.z, w0.w};
            const float w1v[4] = {w1.x, w1.y, w1.z, w1.w};
            const float w2v[4] = {w2.x, w2.y, w2.z, w2.w};
            const float w3v[4] = {w3.x, w3.y, w3.z, w3.w};
            const float w4v[4] = {w4.x, w4.y, w4.z, w4.w};
            const float w5v[4] = {w5.x, w5.y, w5.z, w5.w};

            const float* xf  = x + xb;
            float*       ob0 = out + obB + (size_t)j * Sc + i0;

            for (int f = 0; f < NFc; ++f, xf += PS, ob0 += PS) {
                const float* rm = xf + (size_t)(j - 1) * Sc;
                const float* rc = xf + (size_t)j * Sc;
                const float* rp = xf + (size_t)(j + 1) * Sc;

                const f4 xm = *(const f4*)(rm + i0);
                const f4 xc = *(const f4*)(rc + i0);
                const f4 xp = *(const f4*)(rp + i0);
                const float xml = rm[i0 - 1];
                const float xcl = rc[i0 - 1];
                const float xcr = rc[i0 + 4];
                const float xpr = rp[i0 + 4];

                const float am1[4] = {xml, xm.x, xm.y, xm.z};   // X(j-1, i-1)
                const float acm[4] = {xcl, xc.x, xc.y, xc.z};   // X(j,   i-1)
                const float acp[4] = {xc.y, xc.z, xc.w, xcr};   // X(j,   i+1)
                const float app[4] = {xp.y, xp.z, xp.w, xpr};   // X(j+1, i+1)
                const float xcv[4] = {xc.x, xc.y, xc.z, xc.w};
                const float xmv[4] = {xm.x, xm.y, xm.z, xm.w};
                const float xpv[4] = {xp.x, xp.y, xp.z, xp.w};

                float c0[4], c1[4], c2[4], c3[4];
#pragma unroll
                for (int e = 0; e < 4; ++e) {
                    const float cc = xcv[e];
                    c0[e] = (am1[e] - cc) * w0v[e];
                    c1[e] = (app[e] - cc) * w1v[e];
                    c2[e] = (xmv[e] - cc) * w2v[e] + (acp[e] - cc) * w3v[e];
                    c3[e] = (acm[e] - cc) * w4v[e] + (xpv[e] - cc) * w5v[e];
                }

                f4 o0 = {c0[0], c0[1], c0[2], c0[3]};
                f4 o1 = {c1[0], c1[1], c1[2], c1[3]};
                f4 o2 = {c2[0], c2[1], c2[2], c2[3]};
                f4 o3 = {c3[0], c3[1], c3[2], c3[3]};
                *(f4*)(ob0)          = o0;
                *(f4*)(ob0 + cs)     = o1;
                *(f4*)(ob0 + 2 * cs) = o2;
                *(f4*)(ob0 + 3 * cs) = o3;
            }
        } else if (t == 0) {
            // ---- cols 0..3: col 0 = SE boundary, cols 1..3 inner ----
            const float s0 = wse[0 * 510 + m], s1 = wse[1 * 510 + m];
            const float s2 = wse[2 * 510 + m], s3 = wse[3 * 510 + m];
            const float s4 = wse[4 * 510 + m], s5 = wse[5 * 510 + m];
            float wv[6][3];
#pragma unroll
            for (int k = 0; k < 6; ++k)
#pragma unroll
                for (int e = 0; e < 3; ++e)
                    wv[k][e] = wi[(size_t)k * WSp + (size_t)m * WSr + e];

            const float* xf  = x + xb;
            float*       ob0 = out + obB + (size_t)j * Sc;

            for (int f = 0; f < NFc; ++f, xf += PS, ob0 += PS) {
                const int fp = (f == 0) ? 4 : f - 1;
                const float* xq = x + xb + (size_t)fp * PS + (size_t)(HSc - 1) * Sc;
                const float* rm = xf + (size_t)(j - 1) * Sc;
                const float* rc = xf + (size_t)j * Sc;
                const float* rp = xf + (size_t)(j + 1) * Sc;

                float c0[4], c1[4], c2[4], c3[4];
                {   // SE, col 0
                    const float cc = rc[0];
                    c0[0] = (xq[511 - m] - cc) * s0 + (xq[510 - m] - cc) * s1;
                    c1[0] = (rc[1] - cc) * s2 + (rp[1] - cc) * s3;
                    c2[0] = (rm[0] - cc) * s4;
                    c3[0] = (rp[0] - cc) * s5;
                }
#pragma unroll
                for (int e = 1; e < 4; ++e) {
                    const float cc = rc[e];
                    c0[e] = (rm[e - 1] - cc) * wv[0][e - 1];
                    c1[e] = (rp[e + 1] - cc) * wv[1][e - 1];
                    c2[e] = (rm[e] - cc) * wv[2][e - 1] + (rc[e + 1] - cc) * wv[3][e - 1];
                    c3[e] = (rc[e - 1] - cc) * wv[4][e - 1] + (rp[e] - cc) * wv[5][e - 1];
                }

                f4 o0 = {c0[0], c0[1], c0[2], c0[3]};
                f4 o1 = {c1[0], c1[1], c1[2], c1[3]};
                f4 o2 = {c2[0], c2[1], c2[2], c2[3]};
                f4 o3 = {c3[0], c3[1], c3[2], c3[3]};
                *(f4*)(ob0)          = o0;
                *(f4*)(ob0 + cs)     = o1;
                *(f4*)(ob0 + 2 * cs) = o2;
                *(f4*)(ob0 + 3 * cs) = o3;
            }
        } else {
            // ---- t == 255: cols 1020..1022 inner, col 1023 = NW boundary ----
            const float n0 = wnw[0 * 510 + m], n1 = wnw[1 * 510 + m];
            const float n2 = wnw[2 * 510 + m], n3 = wnw[3 * 510 + m];
            const float n4 = wnw[4 * 510 + m], n5 = wnw[5 * 510 + m];
            float wv[6][3];
#pragma unroll
            for (int k = 0; k < 6; ++k)
#pragma unroll
                for (int e = 0; e < 3; ++e)
                    wv[k][e] = wi[(size_t)k * WSp + (size_t)m * WSr + (1019 + e)];

            const float* xf  = x + xb;
            float*       ob0 = out + obB + (size_t)j * Sc + 1020;

            for (int f = 0; f < NFc; ++f, xf += PS, ob0 += PS) {
                const int fn = (f == 4) ? 0 : f + 1;
                const float* xq = x + xb + (size_t)fn * PS;   // row 0 of next plane
                const float* rm = xf + (size_t)(j - 1) * Sc;
                const float* rc = xf + (size_t)j * Sc;
                const float* rp = xf + (size_t)(j + 1) * Sc;

                float c0[4], c1[4], c2[4], c3[4];
#pragma unroll
                for (int e = 0; e < 3; ++e) {
                    const int i = 1020 + e;
                    const float cc = rc[i];
                    c0[e] = (rm[i - 1] - cc) * wv[0][e];
                    c1[e] = (rp[i + 1] - cc) * wv[1][e];
                    c2[e] = (rm[i] - cc) * wv[2][e] + (rc[i + 1] - cc) * wv[3][e];
                    c3[e] = (rc[i - 1] - cc) * wv[4][e] + (rp[i] - cc) * wv[5][e];
                }
                {   // NW, col 1023
                    const float cc = rc[Sc - 1];
                    c0[3] = (rm[Sc - 2] - cc) * n0;
                    c1[3] = (xq[1022 - m] - cc) * n1;
                    c2[3] = (rm[Sc - 1] - cc) * n2 + (xq[1023 - m] - cc) * n3;
                    c3[3] = (rc[Sc - 2] - cc) * n4 + (rp[Sc - 1] - cc) * n5;
                }

                f4 o0 = {c0[0], c0[1], c0[2], c0[3]};
                f4 o1 = {c1[0], c1[1], c1[2], c1[3]};
                f4 o2 = {c2[0], c2[1], c2[2], c2[3]};
                f4 o3 = {c3[0], c3[1], c3[2], c3[3]};
                *(f4*)(ob0)          = o0;
                *(f4*)(ob0 + cs)     = o1;
                *(f4*)(ob0 + 2 * cs) = o2;
                *(f4*)(ob0 + 3 * cs) = o3;
            }
        }
        return;
    }

    // =============== edge rows j=0 and j=511 (blocks 0..7, scheduled first) ===============
    {
        const int e8 = blockIdx.x;                 // 0..7
        const int j  = (e8 < 4) ? 0 : (HSc - 1);
        const int i  = (e8 & 3) * 256 + t;         // 0..1023
        const size_t obRow = obB + (size_t)j * Sc + (size_t)i;

#define STORE4(ff) do {                                              \
        const size_t _o = obRow + (size_t)(ff) * PS;                 \
        out[_o]          = c0;                                       \
        out[_o + cs]     = c1;                                       \
        out[_o + 2 * cs] = c2;                                       \
        out[_o + 3 * cs] = c3;                                       \
    } while (0)

        if (j == 0) {
            if (i == 0) {
                // ---- CS ----
                const float a0 = wcs[0], a1 = wcs[1], a2 = wcs[2], a3 = wcs[3], a4 = wcs[4];
                for (int f = 0; f < NFc; ++f) {
                    const int fp = (f == 0) ? 4 : f - 1;
                    const float cc = X(f, 0, 0);
                    float c0 = (X(fp, HSc - 1, HSc - 1) - cc) * a0;
                    float c1 = (X(f, 1, 1) - cc) * a1;
                    float c2 = (X(fp, HSc - 1, HSc) - cc) * a2 + (X(f, 0, 1) - cc) * a3;
                    float c3 = (X(f, 1, 0) - cc) * a4;
                    STORE4(f);
                }
            } else if (i <= HSc - 1) {
                // ---- E ----
                const int m = i - 1;
                const float a0 = we[0 * 511 + m], a1 = we[1 * 511 + m];
                const float a2 = we[2 * 511 + m], a3 = we[3 * 511 + m];
                const float a4 = we[4 * 511 + m], a5 = we[5 * 511 + m];
                for (int f = 0; f < NFc; ++f) {
                    const int fp = (f == 0) ? 4 : f - 1;
                    const float cc = X(f, 0, i);
                    float c0 = (X(fp, HSc - 1, HSc + m) - cc) * a0;
                    float c1 = (X(f, 1, i + 1) - cc) * a1;
                    float c2 = (X(fp, HSc - 1, HSc + 1 + m) - cc) * a2
                             + (X(f, 0, i + 1) - cc) * a3;
                    float c3 = (X(f, 0, i - 1) - cc) * a4
                             + (X(f, 1, i)     - cc) * a5;
                    STORE4(f);
                }
            } else if (i == HSc) {
                // ---- CN ----
                const float a0 = wcn[0], a1 = wcn[1], a2 = wcn[2], a3 = wcn[3], a4 = wcn[4];
                for (int f = 0; f < NFc; ++f) {
                    const int fp = (f == 0) ? 4 : f - 1;
                    const float cc = X(f, 0, HSc);
                    float c0 = (X(fp, HSc - 1, Sc - 1) - cc) * a0;
                    float c1 = (X(f, 1, HSc + 1) - cc) * a1;
                    float c2 = (X(f, 0, HSc + 1) - cc) * a2;
                    float c3 = (X(f, 0, HSc - 1) - cc) * a3 + (X(f, 1, HSc) - cc) * a4;
                    STORE4(f);
                }
            } else if (i < Sc - 1) {
                // ---- NE ----
                const int m = i - (HSc + 1);
                const float a0 = wne[0 * 510 + m], a1 = wne[1 * 510 + m];
                const float a2 = wne[2 * 510 + m], a3 = wne[3 * 510 + m];
                const float a4 = wne[4 * 510 + m], a5 = wne[5 * 510 + m];
                for (int f = 0; f < NFc; ++f) {
                    const int fp = (f == 0) ? 4 : f - 1;
                    const float cc = X(f, 0, i);
                    float c0 = (X(fp, 510 - m, Sc - 1) - cc) * a0
                             + (X(fp, 511 - m, Sc - 1) - cc) * a1;
                    float c1 = (X(f, 1, i + 1) - cc) * a2
                             + (X(f, 1, i)     - cc) * a3;
                    float c2 = (X(f, 0, i + 1) - cc) * a4;
                    float c3 = (X(f, 0, i - 1) - cc) * a5;
                    STORE4(f);
                }
            } else {
                // ---- NNE ----
                const float p1 = poles[b * 2 + 1];
                const float a0 = wnne[0], a1 = wnne[1], a2 = wnne[2];
                const float a3 = wnne[3], a4 = wnne[4], a5 = wnne[5];
                for (int f = 0; f < NFc; ++f) {
                    const int fp = (f == 0) ? 4 : f - 1;
                    const int fn = (f == 4) ? 0 : f + 1;
                    const float cc = X(f, 0, Sc - 1);
                    float c0 = (X(fp, 0, Sc - 1) - cc) * a0
                             + (X(fp, 1, Sc - 1) - cc) * a1;
                    float c1 = (X(fn, 0, Sc - 1) - cc) * a2
                             + (X(f,  1, Sc - 1) - cc) * a3;
                    float c2 = (p1 - cc) * a4;
                    float c3 = (X(f, 0, Sc - 2) - cc) * a5;
                    STORE4(f);
                }
            }
        } else { // j == HSc-1
            if (i == 0) {
                // ---- SSE ----
                const float p0 = poles[b * 2 + 0];
                const float a0 = wsse[0], a1 = wsse[1], a2 = wsse[2];
                const float a3 = wsse[3], a4 = wsse[4];
                for (int f = 0; f < NFc; ++f) {
                    const int fp = (f == 0) ? 4 : f - 1;
                    const int fn = (f == 4) ? 0 : f + 1;
                    const float cc = X(f, HSc - 1, 0);
                    float c0 = (X(fp, HSc - 1, 0) - cc) * a0;
                    float c1 = (X(fn, HSc - 1, 0) - cc) * a1;
                    float c2 = (X(f, HSc - 2, 0) - cc) * a2
                             + (X(f, HSc - 1, 1) - cc) * a3;
                    float c3 = (p0 - cc) * a4;
                    STORE4(f);
                }
            } else if (i <= HSc - 1) {
                // ---- SW ----
                const int m = i - 1;
                const float a0 = wsw[0 * 511 + m], a1 = wsw[1 * 511 + m];
                const float a2 = wsw[2 * 511 + m], a3 = wsw[3 * 511 + m];
                const float a4 = wsw[4 * 511 + m], a5 = wsw[5 * 511 + m];
                for (int f = 0; f < NFc; ++f) {
                    const int fn = (f == 4) ? 0 : f + 1;
                    const float cc = X(f, HSc - 1, i);
                    float c0 = (X(f, HSc - 2, i - 1) - cc) * a0;
                    float c1 = (X(fn, 510 - m, 0) - cc) * a1;
                    float c2 = (X(f, HSc - 2, i)     - cc) * a2
                             + (X(f, HSc - 1, i + 1) - cc) * a3;
                    float c3 = (X(f, HSc - 1, i - 1) - cc) * a4
                             + (X(fn, 511 - m, 0)    - cc) * a5;
                    STORE4(f);
                }
            } else if (i < Sc - 1) {
                // ---- WE ----
                const int m = i - HSc;
                const float a0 = wwe[0 * 511 + m], a1 = wwe[1 * 511 + m];
                const float a2 = wwe[2 * 511 + m], a3 = wwe[3 * 511 + m];
                const float a4 = wwe[4 * 511 + m], a5 = wwe[5 * 511 + m];
                for (int f = 0; f < NFc; ++f) {
                    const int fn = (f == 4) ? 0 : f + 1;
                    const float cc = X(f, HSc - 1, i);
                    float c0 = (X(f, HSc - 2, i - 1) - cc) * a0;
                    float c1 = (X(fn, 0, 1 + m) - cc) * a1;
                    float c2 = (X(f, HSc - 2, i)     - cc) * a2
                             + (X(f, HSc - 1, i + 1) - cc) * a3;
                    float c3 = (X(f, HSc - 1, i - 1) - cc) * a4
                             + (X(fn, 0, m)          - cc) * a5;
                    STORE4(f);
                }
            } else {
                // ---- NWW ----
                const float a0 = wnww[0], a1 = wnww[1], a2 = wnww[2];
                const float a3 = wnww[3], a4 = wnww[4], a5 = wnww[5];
                for (int f = 0; f < NFc; ++f) {
                    const int fn = (f == 4) ? 0 : f + 1;
                    const float cc = X(f, HSc - 1, Sc - 1);
                    float c0 = (X(f, HSc - 2, Sc - 2) - cc) * a0;
                    float c1 = (X(fn, 0, HSc) - cc) * a1;
                    float c2 = (X(f, HSc - 2, Sc - 1) - cc) * a2
                             + (X(fn, 0, HSc + 1)     - cc) * a3;
                    float c3 = (X(f, HSc - 1, Sc - 2) - cc) * a4
                             + (X(fn, 0, HSc - 1)     - cc) * a5;
                    STORE4(f);
                }
            }
        }
#undef STORE4
    }
}

extern "C" void kernel_launch(void* const* d_in, const int* in_sizes, int n_in,
                              void* d_out, int out_size, void* d_ws, size_t ws_size,
                              hipStream_t stream) {
    const float* x    = (const float*)d_in[0];
    const float* pl   = (const float*)d_in[1];
    const float* wi   = (const float*)d_in[2];
    const float* we   = (const float*)d_in[3];
    const float* wcn  = (const float*)d_in[4];
    const float* wne  = (const float*)d_in[5];
    const float* wnne = (const float*)d_in[6];
    const float* wnw  = (const float*)d_in[7];
    const float* wnww = (const float*)d_in[8];
    const float* wwe  = (const float*)d_in[9];
    const float* wsw  = (const float*)d_in[10];
    const float* wsse = (const float*)d_in[11];
    const float* wse  = (const float*)d_in[12];
    const float* wcs  = (const float*)d_in[13];
    float* out = (float*)d_out;

    // one fused dispatch: blocks 0..7 = edge rows (scheduled first, overlap with bulk),
    // blocks 8..517 = bulk rows 1..510 (w_inner held in registers across the f-loop)
    icograd_fused<<<dim3(8 + (HSc - 2), Bc, 1), dim3(256, 1, 1), 0, stream>>>(
        x, pl, wi, we, wcn, wne, wnne, wnw, wnww, wwe, wsw, wsse, wse, wcs, out);
}

// Round 3
// 248.021 us; speedup vs baseline: 1.0636x; 1.0636x over previous
//
#include <hip/hip_runtime.h>

#define Bc  4
#define NFc 5
#define HSc 512
#define Sc  1024
#define WSr (Sc - 2)            // 1022, w_inner row length
#define WSp ((HSc - 2) * WSr)   // w_inner plane stride
#define PS  (HSc * Sc)          // x/out plane stride (per f)

typedef float f4 __attribute__((ext_vector_type(4)));

// unaligned (4B-aligned) 16-byte load
static __device__ __forceinline__ f4 load4u(const float* p) {
    f4 r;
    __builtin_memcpy(&r, p, 16);
    return r;
}

// nontemporal 16B store: out is write-once, never re-read -> keep it out of L2/L3
static __device__ __forceinline__ void store4nt(float* p, f4 v) {
    __builtin_nontemporal_store(v, (f4*)p);
}

#define X(ff,jj,ii) x[xb + ((size_t)(ff) * HSc + (size_t)(jj)) * Sc + (size_t)(ii)]

__global__ __launch_bounds__(256) void icograd_fused(
    const float* __restrict__ x,    const float* __restrict__ poles,
    const float* __restrict__ wi,   const float* __restrict__ we,
    const float* __restrict__ wcn,  const float* __restrict__ wne,
    const float* __restrict__ wnne, const float* __restrict__ wnw,
    const float* __restrict__ wnww, const float* __restrict__ wwe,
    const float* __restrict__ wsw,  const float* __restrict__ wsse,
    const float* __restrict__ wse,  const float* __restrict__ wcs,
    float* __restrict__ out)
{
    const int t = threadIdx.x;
    const int b = blockIdx.y;

    const size_t xb  = (size_t)b * (NFc * PS);
    const size_t cs  = (size_t)NFc * PS;                // component stride in out
    const size_t obB = (size_t)b * (4 * NFc) * PS;      // out base for this b

    if (blockIdx.x >= 8) {
        // =============== bulk rows 1..510, one row per block, loop f ===============
        const int j  = blockIdx.x - 7;      // 1..510
        const int m  = j - 1;
        const int i0 = t * 4;

        if (t >= 1 && t <= 254) {
            // ---- vector path: cols i0..i0+3, all inner; w loaded ONCE ----
            const float* wrow = wi + (size_t)m * WSr + (i0 - 1);
            const f4 w0 = load4u(wrow);
            const f4 w1 = load4u(wrow + (size_t)WSp);
            const f4 w2 = load4u(wrow + 2 * (size_t)WSp);
            const f4 w3 = load4u(wrow + 3 * (size_t)WSp);
            const f4 w4 = load4u(wrow + 4 * (size_t)WSp);
            const f4 w5 = load4u(wrow + 5 * (size_t)WSp);
            const float w0v[4] = {w0.x, w0.y, w0.z, w0.w};
            const float w1v[4] = {w1.x, w1.y, w1.z, w1.w};
            const float w2v[4] = {w2.x, w2.y, w2.z, w2.w};
            const float w3v[4] = {w3.x, w3.y, w3.z, w3.w};
            const float w4v[4] = {w4.x, w4.y, w4.z, w4.w};
            const float w5v[4] = {w5.x, w5.y, w5.z, w5.w};

            const float* xf  = x + xb;
            float*       ob0 = out + obB + (size_t)j * Sc + i0;

            // fully unrolled: all 5 planes' independent loads can be batched
            // by the scheduler for maximum memory-level parallelism
#pragma unroll
            for (int f = 0; f < NFc; ++f, xf += PS, ob0 += PS) {
                const float* rm = xf + (size_t)(j - 1) * Sc;
                const float* rc = xf + (size_t)j * Sc;
                const float* rp = xf + (size_t)(j + 1) * Sc;

                const f4 xm = *(const f4*)(rm + i0);
                const f4 xc = *(const f4*)(rc + i0);
                const f4 xp = *(const f4*)(rp + i0);
                const float xml = rm[i0 - 1];
                const float xcl = rc[i0 - 1];
                const float xcr = rc[i0 + 4];
                const float xpr = rp[i0 + 4];

                const float am1[4] = {xml, xm.x, xm.y, xm.z};   // X(j-1, i-1)
                const float acm[4] = {xcl, xc.x, xc.y, xc.z};   // X(j,   i-1)
                const float acp[4] = {xc.y, xc.z, xc.w, xcr};   // X(j,   i+1)
                const float app[4] = {xp.y, xp.z, xp.w, xpr};   // X(j+1, i+1)
                const float xcv[4] = {xc.x, xc.y, xc.z, xc.w};
                const float xmv[4] = {xm.x, xm.y, xm.z, xm.w};
                const float xpv[4] = {xp.x, xp.y, xp.z, xp.w};

                float c0[4], c1[4], c2[4], c3[4];
#pragma unroll
                for (int e = 0; e < 4; ++e) {
                    const float cc = xcv[e];
                    c0[e] = (am1[e] - cc) * w0v[e];
                    c1[e] = (app[e] - cc) * w1v[e];
                    c2[e] = (xmv[e] - cc) * w2v[e] + (acp[e] - cc) * w3v[e];
                    c3[e] = (acm[e] - cc) * w4v[e] + (xpv[e] - cc) * w5v[e];
                }

                f4 o0 = {c0[0], c0[1], c0[2], c0[3]};
                f4 o1 = {c1[0], c1[1], c1[2], c1[3]};
                f4 o2 = {c2[0], c2[1], c2[2], c2[3]};
                f4 o3 = {c3[0], c3[1], c3[2], c3[3]};
                store4nt(ob0,          o0);
                store4nt(ob0 + cs,     o1);
                store4nt(ob0 + 2 * cs, o2);
                store4nt(ob0 + 3 * cs, o3);
            }
        } else if (t == 0) {
            // ---- cols 0..3: col 0 = SE boundary, cols 1..3 inner ----
            const float s0 = wse[0 * 510 + m], s1 = wse[1 * 510 + m];
            const float s2 = wse[2 * 510 + m], s3 = wse[3 * 510 + m];
            const float s4 = wse[4 * 510 + m], s5 = wse[5 * 510 + m];
            float wv[6][3];
#pragma unroll
            for (int k = 0; k < 6; ++k)
#pragma unroll
                for (int e = 0; e < 3; ++e)
                    wv[k][e] = wi[(size_t)k * WSp + (size_t)m * WSr + e];

            const float* xf  = x + xb;
            float*       ob0 = out + obB + (size_t)j * Sc;

#pragma unroll
            for (int f = 0; f < NFc; ++f, xf += PS, ob0 += PS) {
                const int fp = (f == 0) ? 4 : f - 1;
                const float* xq = x + xb + (size_t)fp * PS + (size_t)(HSc - 1) * Sc;
                const float* rm = xf + (size_t)(j - 1) * Sc;
                const float* rc = xf + (size_t)j * Sc;
                const float* rp = xf + (size_t)(j + 1) * Sc;

                float c0[4], c1[4], c2[4], c3[4];
                {   // SE, col 0
                    const float cc = rc[0];
                    c0[0] = (xq[511 - m] - cc) * s0 + (xq[510 - m] - cc) * s1;
                    c1[0] = (rc[1] - cc) * s2 + (rp[1] - cc) * s3;
                    c2[0] = (rm[0] - cc) * s4;
                    c3[0] = (rp[0] - cc) * s5;
                }
#pragma unroll
                for (int e = 1; e < 4; ++e) {
                    const float cc = rc[e];
                    c0[e] = (rm[e - 1] - cc) * wv[0][e - 1];
                    c1[e] = (rp[e + 1] - cc) * wv[1][e - 1];
                    c2[e] = (rm[e] - cc) * wv[2][e - 1] + (rc[e + 1] - cc) * wv[3][e - 1];
                    c3[e] = (rc[e - 1] - cc) * wv[4][e - 1] + (rp[e] - cc) * wv[5][e - 1];
                }

                f4 o0 = {c0[0], c0[1], c0[2], c0[3]};
                f4 o1 = {c1[0], c1[1], c1[2], c1[3]};
                f4 o2 = {c2[0], c2[1], c2[2], c2[3]};
                f4 o3 = {c3[0], c3[1], c3[2], c3[3]};
                store4nt(ob0,          o0);
                store4nt(ob0 + cs,     o1);
                store4nt(ob0 + 2 * cs, o2);
                store4nt(ob0 + 3 * cs, o3);
            }
        } else {
            // ---- t == 255: cols 1020..1022 inner, col 1023 = NW boundary ----
            const float n0 = wnw[0 * 510 + m], n1 = wnw[1 * 510 + m];
            const float n2 = wnw[2 * 510 + m], n3 = wnw[3 * 510 + m];
            const float n4 = wnw[4 * 510 + m], n5 = wnw[5 * 510 + m];
            float wv[6][3];
#pragma unroll
            for (int k = 0; k < 6; ++k)
#pragma unroll
                for (int e = 0; e < 3; ++e)
                    wv[k][e] = wi[(size_t)k * WSp + (size_t)m * WSr + (1019 + e)];

            const float* xf  = x + xb;
            float*       ob0 = out + obB + (size_t)j * Sc + 1020;

#pragma unroll
            for (int f = 0; f < NFc; ++f, xf += PS, ob0 += PS) {
                const int fn = (f == 4) ? 0 : f + 1;
                const float* xq = x + xb + (size_t)fn * PS;   // row 0 of next plane
                const float* rm = xf + (size_t)(j - 1) * Sc;
                const float* rc = xf + (size_t)j * Sc;
                const float* rp = xf + (size_t)(j + 1) * Sc;

                float c0[4], c1[4], c2[4], c3[4];
#pragma unroll
                for (int e = 0; e < 3; ++e) {
                    const int i = 1020 + e;
                    const float cc = rc[i];
                    c0[e] = (rm[i - 1] - cc) * wv[0][e];
                    c1[e] = (rp[i + 1] - cc) * wv[1][e];
                    c2[e] = (rm[i] - cc) * wv[2][e] + (rc[i + 1] - cc) * wv[3][e];
                    c3[e] = (rc[i - 1] - cc) * wv[4][e] + (rp[i] - cc) * wv[5][e];
                }
                {   // NW, col 1023
                    const float cc = rc[Sc - 1];
                    c0[3] = (rm[Sc - 2] - cc) * n0;
                    c1[3] = (xq[1022 - m] - cc) * n1;
                    c2[3] = (rm[Sc - 1] - cc) * n2 + (xq[1023 - m] - cc) * n3;
                    c3[3] = (rc[Sc - 2] - cc) * n4 + (rp[Sc - 1] - cc) * n5;
                }

                f4 o0 = {c0[0], c0[1], c0[2], c0[3]};
                f4 o1 = {c1[0], c1[1], c1[2], c1[3]};
                f4 o2 = {c2[0], c2[1], c2[2], c2[3]};
                f4 o3 = {c3[0], c3[1], c3[2], c3[3]};
                store4nt(ob0,          o0);
                store4nt(ob0 + cs,     o1);
                store4nt(ob0 + 2 * cs, o2);
                store4nt(ob0 + 3 * cs, o3);
            }
        }
        return;
    }

    // =============== edge rows j=0 and j=511 (blocks 0..7, scheduled first) ===============
    {
        const int e8 = blockIdx.x;                 // 0..7
        const int j  = (e8 < 4) ? 0 : (HSc - 1);
        const int i  = (e8 & 3) * 256 + t;         // 0..1023
        const size_t obRow = obB + (size_t)j * Sc + (size_t)i;

#define STORE4(ff) do {                                              \
        float* _o = out + obRow + (size_t)(ff) * PS;                 \
        __builtin_nontemporal_store(c0, _o);                         \
        __builtin_nontemporal_store(c1, _o + cs);                    \
        __builtin_nontemporal_store(c2, _o + 2 * cs);                \
        __builtin_nontemporal_store(c3, _o + 3 * cs);                \
    } while (0)

        if (j == 0) {
            if (i == 0) {
                // ---- CS ----
                const float a0 = wcs[0], a1 = wcs[1], a2 = wcs[2], a3 = wcs[3], a4 = wcs[4];
                for (int f = 0; f < NFc; ++f) {
                    const int fp = (f == 0) ? 4 : f - 1;
                    const float cc = X(f, 0, 0);
                    float c0 = (X(fp, HSc - 1, HSc - 1) - cc) * a0;
                    float c1 = (X(f, 1, 1) - cc) * a1;
                    float c2 = (X(fp, HSc - 1, HSc) - cc) * a2 + (X(f, 0, 1) - cc) * a3;
                    float c3 = (X(f, 1, 0) - cc) * a4;
                    STORE4(f);
                }
            } else if (i <= HSc - 1) {
                // ---- E ----
                const int m = i - 1;
                const float a0 = we[0 * 511 + m], a1 = we[1 * 511 + m];
                const float a2 = we[2 * 511 + m], a3 = we[3 * 511 + m];
                const float a4 = we[4 * 511 + m], a5 = we[5 * 511 + m];
                for (int f = 0; f < NFc; ++f) {
                    const int fp = (f == 0) ? 4 : f - 1;
                    const float cc = X(f, 0, i);
                    float c0 = (X(fp, HSc - 1, HSc + m) - cc) * a0;
                    float c1 = (X(f, 1, i + 1) - cc) * a1;
                    float c2 = (X(fp, HSc - 1, HSc + 1 + m) - cc) * a2
                             + (X(f, 0, i + 1) - cc) * a3;
                    float c3 = (X(f, 0, i - 1) - cc) * a4
                             + (X(f, 1, i)     - cc) * a5;
                    STORE4(f);
                }
            } else if (i == HSc) {
                // ---- CN ----
                const float a0 = wcn[0], a1 = wcn[1], a2 = wcn[2], a3 = wcn[3], a4 = wcn[4];
                for (int f = 0; f < NFc; ++f) {
                    const int fp = (f == 0) ? 4 : f - 1;
                    const float cc = X(f, 0, HSc);
                    float c0 = (X(fp, HSc - 1, Sc - 1) - cc) * a0;
                    float c1 = (X(f, 1, HSc + 1) - cc) * a1;
                    float c2 = (X(f, 0, HSc + 1) - cc) * a2;
                    float c3 = (X(f, 0, HSc - 1) - cc) * a3 + (X(f, 1, HSc) - cc) * a4;
                    STORE4(f);
                }
            } else if (i < Sc - 1) {
                // ---- NE ----
                const int m = i - (HSc + 1);
                const float a0 = wne[0 * 510 + m], a1 = wne[1 * 510 + m];
                const float a2 = wne[2 * 510 + m], a3 = wne[3 * 510 + m];
                const float a4 = wne[4 * 510 + m], a5 = wne[5 * 510 + m];
                for (int f = 0; f < NFc; ++f) {
                    const int fp = (f == 0) ? 4 : f - 1;
                    const float cc = X(f, 0, i);
                    float c0 = (X(fp, 510 - m, Sc - 1) - cc) * a0
                             + (X(fp, 511 - m, Sc - 1) - cc) * a1;
                    float c1 = (X(f, 1, i + 1) - cc) * a2
                             + (X(f, 1, i)     - cc) * a3;
                    float c2 = (X(f, 0, i + 1) - cc) * a4;
                    float c3 = (X(f, 0, i - 1) - cc) * a5;
                    STORE4(f);
                }
            } else {
                // ---- NNE ----
                const float p1 = poles[b * 2 + 1];
                const float a0 = wnne[0], a1 = wnne[1], a2 = wnne[2];
                const float a3 = wnne[3], a4 = wnne[4], a5 = wnne[5];
                for (int f = 0; f < NFc; ++f) {
                    const int fp = (f == 0) ? 4 : f - 1;
                    const int fn = (f == 4) ? 0 : f + 1;
                    const float cc = X(f, 0, Sc - 1);
                    float c0 = (X(fp, 0, Sc - 1) - cc) * a0
                             + (X(fp, 1, Sc - 1) - cc) * a1;
                    float c1 = (X(fn, 0, Sc - 1) - cc) * a2
                             + (X(f,  1, Sc - 1) - cc) * a3;
                    float c2 = (p1 - cc) * a4;
                    float c3 = (X(f, 0, Sc - 2) - cc) * a5;
                    STORE4(f);
                }
            }
        } else { // j == HSc-1
            if (i == 0) {
                // ---- SSE ----
                const float p0 = poles[b * 2 + 0];
                const float a0 = wsse[0], a1 = wsse[1], a2 = wsse[2];
                const float a3 = wsse[3], a4 = wsse[4];
                for (int f = 0; f < NFc; ++f) {
                    const int fp = (f == 0) ? 4 : f - 1;
                    const int fn = (f == 4) ? 0 : f + 1;
                    const float cc = X(f, HSc - 1, 0);
                    float c0 = (X(fp, HSc - 1, 0) - cc) * a0;
                    float c1 = (X(fn, HSc - 1, 0) - cc) * a1;
                    float c2 = (X(f, HSc - 2, 0) - cc) * a2
                             + (X(f, HSc - 1, 1) - cc) * a3;
                    float c3 = (p0 - cc) * a4;
                    STORE4(f);
                }
            } else if (i <= HSc - 1) {
                // ---- SW ----
                const int m = i - 1;
                const float a0 = wsw[0 * 511 + m], a1 = wsw[1 * 511 + m];
                const float a2 = wsw[2 * 511 + m], a3 = wsw[3 * 511 + m];
                const float a4 = wsw[4 * 511 + m], a5 = wsw[5 * 511 + m];
                for (int f = 0; f < NFc; ++f) {
                    const int fn = (f == 4) ? 0 : f + 1;
                    const float cc = X(f, HSc - 1, i);
                    float c0 = (X(f, HSc - 2, i - 1) - cc) * a0;
                    float c1 = (X(fn, 510 - m, 0) - cc) * a1;
                    float c2 = (X(f, HSc - 2, i)     - cc) * a2
                             + (X(f, HSc - 1, i + 1) - cc) * a3;
                    float c3 = (X(f, HSc - 1, i - 1) - cc) * a4
                             + (X(fn, 511 - m, 0)    - cc) * a5;
                    STORE4(f);
                }
            } else if (i < Sc - 1) {
                // ---- WE ----
                const int m = i - HSc;
                const float a0 = wwe[0 * 511 + m], a1 = wwe[1 * 511 + m];
                const float a2 = wwe[2 * 511 + m], a3 = wwe[3 * 511 + m];
                const float a4 = wwe[4 * 511 + m], a5 = wwe[5 * 511 + m];
                for (int f = 0; f < NFc; ++f) {
                    const int fn = (f == 4) ? 0 : f + 1;
                    const float cc = X(f, HSc - 1, i);
                    float c0 = (X(f, HSc - 2, i - 1) - cc) * a0;
                    float c1 = (X(fn, 0, 1 + m) - cc) * a1;
                    float c2 = (X(f, HSc - 2, i)     - cc) * a2
                             + (X(f, HSc - 1, i + 1) - cc) * a3;
                    float c3 = (X(f, HSc - 1, i - 1) - cc) * a4
                             + (X(fn, 0, m)          - cc) * a5;
                    STORE4(f);
                }
            } else {
                // ---- NWW ----
                const float a0 = wnww[0], a1 = wnww[1], a2 = wnww[2];
                const float a3 = wnww[3], a4 = wnww[4], a5 = wnww[5];
                for (int f = 0; f < NFc; ++f) {
                    const int fn = (f == 4) ? 0 : f + 1;
                    const float cc = X(f, HSc - 1, Sc - 1);
                    float c0 = (X(f, HSc - 2, Sc - 2) - cc) * a0;
                    float c1 = (X(fn, 0, HSc) - cc) * a1;
                    float c2 = (X(f, HSc - 2, Sc - 1) - cc) * a2
                             + (X(fn, 0, HSc + 1)     - cc) * a3;
                    float c3 = (X(f, HSc - 1, Sc - 2) - cc) * a4
                             + (X(fn, 0, HSc - 1)     - cc) * a5;
                    STORE4(f);
                }
            }
        }
#undef STORE4
    }
}

extern "C" void kernel_launch(void* const* d_in, const int* in_sizes, int n_in,
                              void* d_out, int out_size, void* d_ws, size_t ws_size,
                              hipStream_t stream) {
    const float* x    = (const float*)d_in[0];
    const float* pl   = (const float*)d_in[1];
    const float* wi   = (const float*)d_in[2];
    const float* we   = (const float*)d_in[3];
    const float* wcn  = (const float*)d_in[4];
    const float* wne  = (const float*)d_in[5];
    const float* wnne = (const float*)d_in[6];
    const float* wnw  = (const float*)d_in[7];
    const float* wnww = (const float*)d_in[8];
    const float* wwe  = (const float*)d_in[9];
    const float* wsw  = (const float*)d_in[10];
    const float* wsse = (const float*)d_in[11];
    const float* wse  = (const float*)d_in[12];
    const float* wcs  = (const float*)d_in[13];
    float* out = (float*)d_out;

    // one fused dispatch: blocks 0..7 = edge rows (scheduled first, overlap with bulk),
    // blocks 8..517 = bulk rows 1..510 (w_inner held in registers, f-loop unrolled,
    // nontemporal stores keep the 168 MB output stream out of L2/L3)
    icograd_fused<<<dim3(8 + (HSc - 2), Bc, 1), dim3(256, 1, 1), 0, stream>>>(
        x, pl, wi, we, wcn, wne, wnne, wnw, wnww, wwe, wsw, wsse, wse, wcs, out);
}

// Round 4
// 247.879 us; speedup vs baseline: 1.0642x; 1.0006x over previous
//
#include <hip/hip_runtime.h>

#define Bc  4
#define NFc 5
#define HSc 512
#define Sc  1024
#define WSr (Sc - 2)            // 1022, w_inner row length
#define WSp ((HSc - 2) * WSr)   // w_inner plane stride
#define PS  (HSc * Sc)          // x/out plane stride (per f)

typedef float f4 __attribute__((ext_vector_type(4)));

// unaligned (4B-aligned) 16-byte load
static __device__ __forceinline__ f4 load4u(const float* p) {
    f4 r;
    __builtin_memcpy(&r, p, 16);
    return r;
}

// nontemporal 16B store: out is write-once, never re-read -> keep it out of L2/L3
static __device__ __forceinline__ void store4nt(float* p, f4 v) {
    __builtin_nontemporal_store(v, (f4*)p);
}

#define X(ff,jj,ii) x[xb + ((size_t)(ff) * HSc + (size_t)(jj)) * Sc + (size_t)(ii)]

__global__ __launch_bounds__(256) void icograd_fused(
    const float* __restrict__ x,    const float* __restrict__ poles,
    const float* __restrict__ wi,   const float* __restrict__ we,
    const float* __restrict__ wcn,  const float* __restrict__ wne,
    const float* __restrict__ wnne, const float* __restrict__ wnw,
    const float* __restrict__ wnww, const float* __restrict__ wwe,
    const float* __restrict__ wsw,  const float* __restrict__ wsse,
    const float* __restrict__ wse,  const float* __restrict__ wcs,
    float* __restrict__ out)
{
    const int t = threadIdx.x;
    const int b = blockIdx.y;

    const size_t xb  = (size_t)b * (NFc * PS);
    const size_t cs  = (size_t)NFc * PS;                // component stride in out
    const size_t obB = (size_t)b * (4 * NFc) * PS;      // out base for this b

    if (blockIdx.x >= 8) {
        // =============== bulk rows 1..510, one row per block, loop f ===============
        // XCD-aware bijective chunked swizzle of the 510 bulk rows (510 = 8*63+6):
        // round-robin XCD assignment -> each XCD owns a CONTIGUOUS j-range, so
        // adjacent-j blocks (sharing 2 of 3 stencil rows per plane) hit the same L2.
        const int jl  = blockIdx.x - 8;          // 0..509, round-robins XCDs
        const int xcd = jl & 7;
        const int idx = jl >> 3;
        const int jp  = (xcd < 6) ? (xcd * 64 + idx)
                                  : (384 + (xcd - 6) * 63 + idx);
        const int j  = jp + 1;                   // 1..510
        const int m  = j - 1;
        const int i0 = t * 4;

        if (t >= 1 && t <= 254) {
            // ---- vector path: cols i0..i0+3, all inner; w loaded ONCE ----
            const float* wrow = wi + (size_t)m * WSr + (i0 - 1);
            const f4 w0 = load4u(wrow);
            const f4 w1 = load4u(wrow + (size_t)WSp);
            const f4 w2 = load4u(wrow + 2 * (size_t)WSp);
            const f4 w3 = load4u(wrow + 3 * (size_t)WSp);
            const f4 w4 = load4u(wrow + 4 * (size_t)WSp);
            const f4 w5 = load4u(wrow + 5 * (size_t)WSp);
            const float w0v[4] = {w0.x, w0.y, w0.z, w0.w};
            const float w1v[4] = {w1.x, w1.y, w1.z, w1.w};
            const float w2v[4] = {w2.x, w2.y, w2.z, w2.w};
            const float w3v[4] = {w3.x, w3.y, w3.z, w3.w};
            const float w4v[4] = {w4.x, w4.y, w4.z, w4.w};
            const float w5v[4] = {w5.x, w5.y, w5.z, w5.w};

            const float* xf  = x + xb;
            float*       ob0 = out + obB + (size_t)j * Sc + i0;

            // fully unrolled: all 5 planes' independent loads can be batched
            // by the scheduler for maximum memory-level parallelism
#pragma unroll
            for (int f = 0; f < NFc; ++f, xf += PS, ob0 += PS) {
                const float* rm = xf + (size_t)(j - 1) * Sc;
                const float* rc = xf + (size_t)j * Sc;
                const float* rp = xf + (size_t)(j + 1) * Sc;

                const f4 xm = *(const f4*)(rm + i0);
                const f4 xc = *(const f4*)(rc + i0);
                const f4 xp = *(const f4*)(rp + i0);
                const float xml = rm[i0 - 1];
                const float xcl = rc[i0 - 1];
                const float xcr = rc[i0 + 4];
                const float xpr = rp[i0 + 4];

                const float am1[4] = {xml, xm.x, xm.y, xm.z};   // X(j-1, i-1)
                const float acm[4] = {xcl, xc.x, xc.y, xc.z};   // X(j,   i-1)
                const float acp[4] = {xc.y, xc.z, xc.w, xcr};   // X(j,   i+1)
                const float app[4] = {xp.y, xp.z, xp.w, xpr};   // X(j+1, i+1)
                const float xcv[4] = {xc.x, xc.y, xc.z, xc.w};
                const float xmv[4] = {xm.x, xm.y, xm.z, xm.w};
                const float xpv[4] = {xp.x, xp.y, xp.z, xp.w};

                float c0[4], c1[4], c2[4], c3[4];
#pragma unroll
                for (int e = 0; e < 4; ++e) {
                    const float cc = xcv[e];
                    c0[e] = (am1[e] - cc) * w0v[e];
                    c1[e] = (app[e] - cc) * w1v[e];
                    c2[e] = (xmv[e] - cc) * w2v[e] + (acp[e] - cc) * w3v[e];
                    c3[e] = (acm[e] - cc) * w4v[e] + (xpv[e] - cc) * w5v[e];
                }

                f4 o0 = {c0[0], c0[1], c0[2], c0[3]};
                f4 o1 = {c1[0], c1[1], c1[2], c1[3]};
                f4 o2 = {c2[0], c2[1], c2[2], c2[3]};
                f4 o3 = {c3[0], c3[1], c3[2], c3[3]};
                store4nt(ob0,          o0);
                store4nt(ob0 + cs,     o1);
                store4nt(ob0 + 2 * cs, o2);
                store4nt(ob0 + 3 * cs, o3);
            }
        } else if (t == 0) {
            // ---- cols 0..3: col 0 = SE boundary, cols 1..3 inner ----
            const float s0 = wse[0 * 510 + m], s1 = wse[1 * 510 + m];
            const float s2 = wse[2 * 510 + m], s3 = wse[3 * 510 + m];
            const float s4 = wse[4 * 510 + m], s5 = wse[5 * 510 + m];
            float wv[6][3];
#pragma unroll
            for (int k = 0; k < 6; ++k)
#pragma unroll
                for (int e = 0; e < 3; ++e)
                    wv[k][e] = wi[(size_t)k * WSp + (size_t)m * WSr + e];

            const float* xf  = x + xb;
            float*       ob0 = out + obB + (size_t)j * Sc;

#pragma unroll
            for (int f = 0; f < NFc; ++f, xf += PS, ob0 += PS) {
                const int fp = (f == 0) ? 4 : f - 1;
                const float* xq = x + xb + (size_t)fp * PS + (size_t)(HSc - 1) * Sc;
                const float* rm = xf + (size_t)(j - 1) * Sc;
                const float* rc = xf + (size_t)j * Sc;
                const float* rp = xf + (size_t)(j + 1) * Sc;

                float c0[4], c1[4], c2[4], c3[4];
                {   // SE, col 0
                    const float cc = rc[0];
                    c0[0] = (xq[511 - m] - cc) * s0 + (xq[510 - m] - cc) * s1;
                    c1[0] = (rc[1] - cc) * s2 + (rp[1] - cc) * s3;
                    c2[0] = (rm[0] - cc) * s4;
                    c3[0] = (rp[0] - cc) * s5;
                }
#pragma unroll
                for (int e = 1; e < 4; ++e) {
                    const float cc = rc[e];
                    c0[e] = (rm[e - 1] - cc) * wv[0][e - 1];
                    c1[e] = (rp[e + 1] - cc) * wv[1][e - 1];
                    c2[e] = (rm[e] - cc) * wv[2][e - 1] + (rc[e + 1] - cc) * wv[3][e - 1];
                    c3[e] = (rc[e - 1] - cc) * wv[4][e - 1] + (rp[e] - cc) * wv[5][e - 1];
                }

                f4 o0 = {c0[0], c0[1], c0[2], c0[3]};
                f4 o1 = {c1[0], c1[1], c1[2], c1[3]};
                f4 o2 = {c2[0], c2[1], c2[2], c2[3]};
                f4 o3 = {c3[0], c3[1], c3[2], c3[3]};
                store4nt(ob0,          o0);
                store4nt(ob0 + cs,     o1);
                store4nt(ob0 + 2 * cs, o2);
                store4nt(ob0 + 3 * cs, o3);
            }
        } else {
            // ---- t == 255: cols 1020..1022 inner, col 1023 = NW boundary ----
            const float n0 = wnw[0 * 510 + m], n1 = wnw[1 * 510 + m];
            const float n2 = wnw[2 * 510 + m], n3 = wnw[3 * 510 + m];
            const float n4 = wnw[4 * 510 + m], n5 = wnw[5 * 510 + m];
            float wv[6][3];
#pragma unroll
            for (int k = 0; k < 6; ++k)
#pragma unroll
                for (int e = 0; e < 3; ++e)
                    wv[k][e] = wi[(size_t)k * WSp + (size_t)m * WSr + (1019 + e)];

            const float* xf  = x + xb;
            float*       ob0 = out + obB + (size_t)j * Sc + 1020;

#pragma unroll
            for (int f = 0; f < NFc; ++f, xf += PS, ob0 += PS) {
                const int fn = (f == 4) ? 0 : f + 1;
                const float* xq = x + xb + (size_t)fn * PS;   // row 0 of next plane
                const float* rm = xf + (size_t)(j - 1) * Sc;
                const float* rc = xf + (size_t)j * Sc;
                const float* rp = xf + (size_t)(j + 1) * Sc;

                float c0[4], c1[4], c2[4], c3[4];
#pragma unroll
                for (int e = 0; e < 3; ++e) {
                    const int i = 1020 + e;
                    const float cc = rc[i];
                    c0[e] = (rm[i - 1] - cc) * wv[0][e];
                    c1[e] = (rp[i + 1] - cc) * wv[1][e];
                    c2[e] = (rm[i] - cc) * wv[2][e] + (rc[i + 1] - cc) * wv[3][e];
                    c3[e] = (rc[i - 1] - cc) * wv[4][e] + (rp[i] - cc) * wv[5][e];
                }
                {   // NW, col 1023
                    const float cc = rc[Sc - 1];
                    c0[3] = (rm[Sc - 2] - cc) * n0;
                    c1[3] = (xq[1022 - m] - cc) * n1;
                    c2[3] = (rm[Sc - 1] - cc) * n2 + (xq[1023 - m] - cc) * n3;
                    c3[3] = (rc[Sc - 2] - cc) * n4 + (rp[Sc - 1] - cc) * n5;
                }

                f4 o0 = {c0[0], c0[1], c0[2], c0[3]};
                f4 o1 = {c1[0], c1[1], c1[2], c1[3]};
                f4 o2 = {c2[0], c2[1], c2[2], c2[3]};
                f4 o3 = {c3[0], c3[1], c3[2], c3[3]};
                store4nt(ob0,          o0);
                store4nt(ob0 + cs,     o1);
                store4nt(ob0 + 2 * cs, o2);
                store4nt(ob0 + 3 * cs, o3);
            }
        }
        return;
    }

    // =============== edge rows j=0 and j=511 (blocks 0..7, scheduled first) ===============
    {
        const int e8 = blockIdx.x;                 // 0..7
        const int j  = (e8 < 4) ? 0 : (HSc - 1);
        const int i  = (e8 & 3) * 256 + t;         // 0..1023
        const size_t obRow = obB + (size_t)j * Sc + (size_t)i;

#define STORE4(ff) do {                                              \
        float* _o = out + obRow + (size_t)(ff) * PS;                 \
        __builtin_nontemporal_store(c0, _o);                         \
        __builtin_nontemporal_store(c1, _o + cs);                    \
        __builtin_nontemporal_store(c2, _o + 2 * cs);                \
        __builtin_nontemporal_store(c3, _o + 3 * cs);                \
    } while (0)

        if (j == 0) {
            if (i == 0) {
                // ---- CS ----
                const float a0 = wcs[0], a1 = wcs[1], a2 = wcs[2], a3 = wcs[3], a4 = wcs[4];
                for (int f = 0; f < NFc; ++f) {
                    const int fp = (f == 0) ? 4 : f - 1;
                    const float cc = X(f, 0, 0);
                    float c0 = (X(fp, HSc - 1, HSc - 1) - cc) * a0;
                    float c1 = (X(f, 1, 1) - cc) * a1;
                    float c2 = (X(fp, HSc - 1, HSc) - cc) * a2 + (X(f, 0, 1) - cc) * a3;
                    float c3 = (X(f, 1, 0) - cc) * a4;
                    STORE4(f);
                }
            } else if (i <= HSc - 1) {
                // ---- E ----
                const int m = i - 1;
                const float a0 = we[0 * 511 + m], a1 = we[1 * 511 + m];
                const float a2 = we[2 * 511 + m], a3 = we[3 * 511 + m];
                const float a4 = we[4 * 511 + m], a5 = we[5 * 511 + m];
                for (int f = 0; f < NFc; ++f) {
                    const int fp = (f == 0) ? 4 : f - 1;
                    const float cc = X(f, 0, i);
                    float c0 = (X(fp, HSc - 1, HSc + m) - cc) * a0;
                    float c1 = (X(f, 1, i + 1) - cc) * a1;
                    float c2 = (X(fp, HSc - 1, HSc + 1 + m) - cc) * a2
                             + (X(f, 0, i + 1) - cc) * a3;
                    float c3 = (X(f, 0, i - 1) - cc) * a4
                             + (X(f, 1, i)     - cc) * a5;
                    STORE4(f);
                }
            } else if (i == HSc) {
                // ---- CN ----
                const float a0 = wcn[0], a1 = wcn[1], a2 = wcn[2], a3 = wcn[3], a4 = wcn[4];
                for (int f = 0; f < NFc; ++f) {
                    const int fp = (f == 0) ? 4 : f - 1;
                    const float cc = X(f, 0, HSc);
                    float c0 = (X(fp, HSc - 1, Sc - 1) - cc) * a0;
                    float c1 = (X(f, 1, HSc + 1) - cc) * a1;
                    float c2 = (X(f, 0, HSc + 1) - cc) * a2;
                    float c3 = (X(f, 0, HSc - 1) - cc) * a3 + (X(f, 1, HSc) - cc) * a4;
                    STORE4(f);
                }
            } else if (i < Sc - 1) {
                // ---- NE ----
                const int m = i - (HSc + 1);
                const float a0 = wne[0 * 510 + m], a1 = wne[1 * 510 + m];
                const float a2 = wne[2 * 510 + m], a3 = wne[3 * 510 + m];
                const float a4 = wne[4 * 510 + m], a5 = wne[5 * 510 + m];
                for (int f = 0; f < NFc; ++f) {
                    const int fp = (f == 0) ? 4 : f - 1;
                    const float cc = X(f, 0, i);
                    float c0 = (X(fp, 510 - m, Sc - 1) - cc) * a0
                             + (X(fp, 511 - m, Sc - 1) - cc) * a1;
                    float c1 = (X(f, 1, i + 1) - cc) * a2
                             + (X(f, 1, i)     - cc) * a3;
                    float c2 = (X(f, 0, i + 1) - cc) * a4;
                    float c3 = (X(f, 0, i - 1) - cc) * a5;
                    STORE4(f);
                }
            } else {
                // ---- NNE ----
                const float p1 = poles[b * 2 + 1];
                const float a0 = wnne[0], a1 = wnne[1], a2 = wnne[2];
                const float a3 = wnne[3], a4 = wnne[4], a5 = wnne[5];
                for (int f = 0; f < NFc; ++f) {
                    const int fp = (f == 0) ? 4 : f - 1;
                    const int fn = (f == 4) ? 0 : f + 1;
                    const float cc = X(f, 0, Sc - 1);
                    float c0 = (X(fp, 0, Sc - 1) - cc) * a0
                             + (X(fp, 1, Sc - 1) - cc) * a1;
                    float c1 = (X(fn, 0, Sc - 1) - cc) * a2
                             + (X(f,  1, Sc - 1) - cc) * a3;
                    float c2 = (p1 - cc) * a4;
                    float c3 = (X(f, 0, Sc - 2) - cc) * a5;
                    STORE4(f);
                }
            }
        } else { // j == HSc-1
            if (i == 0) {
                // ---- SSE ----
                const float p0 = poles[b * 2 + 0];
                const float a0 = wsse[0], a1 = wsse[1], a2 = wsse[2];
                const float a3 = wsse[3], a4 = wsse[4];
                for (int f = 0; f < NFc; ++f) {
                    const int fp = (f == 0) ? 4 : f - 1;
                    const int fn = (f == 4) ? 0 : f + 1;
                    const float cc = X(f, HSc - 1, 0);
                    float c0 = (X(fp, HSc - 1, 0) - cc) * a0;
                    float c1 = (X(fn, HSc - 1, 0) - cc) * a1;
                    float c2 = (X(f, HSc - 2, 0) - cc) * a2
                             + (X(f, HSc - 1, 1) - cc) * a3;
                    float c3 = (p0 - cc) * a4;
                    STORE4(f);
                }
            } else if (i <= HSc - 1) {
                // ---- SW ----
                const int m = i - 1;
                const float a0 = wsw[0 * 511 + m], a1 = wsw[1 * 511 + m];
                const float a2 = wsw[2 * 511 + m], a3 = wsw[3 * 511 + m];
                const float a4 = wsw[4 * 511 + m], a5 = wsw[5 * 511 + m];
                for (int f = 0; f < NFc; ++f) {
                    const int fn = (f == 4) ? 0 : f + 1;
                    const float cc = X(f, HSc - 1, i);
                    float c0 = (X(f, HSc - 2, i - 1) - cc) * a0;
                    float c1 = (X(fn, 510 - m, 0) - cc) * a1;
                    float c2 = (X(f, HSc - 2, i)     - cc) * a2
                             + (X(f, HSc - 1, i + 1) - cc) * a3;
                    float c3 = (X(f, HSc - 1, i - 1) - cc) * a4
                             + (X(fn, 511 - m, 0)    - cc) * a5;
                    STORE4(f);
                }
            } else if (i < Sc - 1) {
                // ---- WE ----
                const int m = i - HSc;
                const float a0 = wwe[0 * 511 + m], a1 = wwe[1 * 511 + m];
                const float a2 = wwe[2 * 511 + m], a3 = wwe[3 * 511 + m];
                const float a4 = wwe[4 * 511 + m], a5 = wwe[5 * 511 + m];
                for (int f = 0; f < NFc; ++f) {
                    const int fn = (f == 4) ? 0 : f + 1;
                    const float cc = X(f, HSc - 1, i);
                    float c0 = (X(f, HSc - 2, i - 1) - cc) * a0;
                    float c1 = (X(fn, 0, 1 + m) - cc) * a1;
                    float c2 = (X(f, HSc - 2, i)     - cc) * a2
                             + (X(f, HSc - 1, i + 1) - cc) * a3;
                    float c3 = (X(f, HSc - 1, i - 1) - cc) * a4
                             + (X(fn, 0, m)          - cc) * a5;
                    STORE4(f);
                }
            } else {
                // ---- NWW ----
                const float a0 = wnww[0], a1 = wnww[1], a2 = wnww[2];
                const float a3 = wnww[3], a4 = wnww[4], a5 = wnww[5];
                for (int f = 0; f < NFc; ++f) {
                    const int fn = (f == 4) ? 0 : f + 1;
                    const float cc = X(f, HSc - 1, Sc - 1);
                    float c0 = (X(f, HSc - 2, Sc - 2) - cc) * a0;
                    float c1 = (X(fn, 0, HSc) - cc) * a1;
                    float c2 = (X(f, HSc - 2, Sc - 1) - cc) * a2
                             + (X(fn, 0, HSc + 1)     - cc) * a3;
                    float c3 = (X(f, HSc - 1, Sc - 2) - cc) * a4
                             + (X(fn, 0, HSc - 1)     - cc) * a5;
                    STORE4(f);
                }
            }
        }
#undef STORE4
    }
}

extern "C" void kernel_launch(void* const* d_in, const int* in_sizes, int n_in,
                              void* d_out, int out_size, void* d_ws, size_t ws_size,
                              hipStream_t stream) {
    const float* x    = (const float*)d_in[0];
    const float* pl   = (const float*)d_in[1];
    const float* wi   = (const float*)d_in[2];
    const float* we   = (const float*)d_in[3];
    const float* wcn  = (const float*)d_in[4];
    const float* wne  = (const float*)d_in[5];
    const float* wnne = (const float*)d_in[6];
    const float* wnw  = (const float*)d_in[7];
    const float* wnww = (const float*)d_in[8];
    const float* wwe  = (const float*)d_in[9];
    const float* wsw  = (const float*)d_in[10];
    const float* wsse = (const float*)d_in[11];
    const float* wse  = (const float*)d_in[12];
    const float* wcs  = (const float*)d_in[13];
    float* out = (float*)d_out;

    // one fused dispatch: blocks 0..7 = edge rows (scheduled first, overlap with bulk),
    // blocks 8..517 = bulk rows 1..510 (XCD-chunked j order, w_inner in registers,
    // f-loop unrolled, nontemporal stores keep the 168 MB output out of L2/L3)
    icograd_fused<<<dim3(8 + (HSc - 2), Bc, 1), dim3(256, 1, 1), 0, stream>>>(
        x, pl, wi, we, wcn, wne, wnne, wnw, wnww, wwe, wsw, wsse, wse, wcs, out);
}